// Round 6
// baseline (326.112 us; speedup 1.0000x reference)
//
#include <hip/hip_runtime.h>
#include <stdint.h>

#define IN_SIZE 224
#define KER 5
#define IN_CH 16
#define OUT_CH 64
#define NH 220
#define NB_TILES (NH * NH)       // 48400
#define XCH (IN_SIZE * IN_SIZE)  // 50176
#define OUT_PLANE NB_TILES
#define YSTRIDE 49280            // 220*224: bf16 y, row-padded to 224 (pad cols zeroed)
#define LR_OVER_NB ((float)(0.005 / 48400.0))
#define GAMMA_F 0.99f
#define ONE_MINUS_GAMMA 0.01f
#define EPS_F 0.01f

// fused GEMM: y^T (64 x K) @ [xf | y] (K x 464), K = 49280
#define NTOT 464
#define NCHUNK 28
#define KCHUNK 1760              // 55 steps of 32
#define PSTRIDE (OUT_CH * NTOT)  // 29696 = 116*256

typedef __attribute__((ext_vector_type(8))) short short8;
typedef __attribute__((ext_vector_type(4))) float floatx4;

__device__ inline uint16_t f2bf(float f) {
    uint32_t u = __float_as_uint(f);
    return (uint16_t)((u + 0x7FFFu + ((u >> 16) & 1u)) >> 16);
}

// ---------------- Kernel 0: cast x to bf16 (+pads), zero y-pad columns ----------------
__global__ __launch_bounds__(256) void xcast_kernel(const float* __restrict__ x,
                                                    uint16_t* __restrict__ xb,
                                                    uint16_t* __restrict__ yb) {
    int t = blockIdx.x * 256 + threadIdx.x;
    if (t < XCH * IN_CH / 4) {
        float4 v = ((const float4*)x)[t];
        ushort4 o;
        o.x = f2bf(v.x); o.y = f2bf(v.y); o.z = f2bf(v.z); o.w = f2bf(v.w);
        ((ushort4*)xb)[t] = o;
    }
    if (t < 32) {  // zero 128-elem tail pad of xb
        ushort4 z = {0, 0, 0, 0};
        ((ushort4*)(xb + XCH * IN_CH))[t] = z;
    }
    if (t < OUT_CH * NH) {  // zero y pad columns j=220..223
        int o = t / NH, i = t - o * NH;
        ushort4 z = {0, 0, 0, 0};
        *(ushort4*)(yb + o * YSTRIDE + i * IN_SIZE + NH) = z;
    }
}

// ---------------- Kernel 1: conv, 64x64 tile, 4x4 micro-tile, 1 oc/block ----------------
__global__ __launch_bounds__(256) void conv_kernel(const float* __restrict__ x,
                                                   const float* __restrict__ W,
                                                   float* __restrict__ out) {
    __shared__ float xs[68 * 68];
    const int tx = threadIdx.x & 15;
    const int ty = threadIdx.x >> 4;
    const int ti = blockIdx.y * 64;
    const int tj = blockIdx.x * 64;
    const int oc = blockIdx.z;

    float acc[16];
#pragma unroll
    for (int i = 0; i < 16; i++) acc[i] = 0.f;
    const float* W0 = W + oc * 400;

    for (int c = 0; c < IN_CH; c++) {
        __syncthreads();
        for (int s = threadIdx.x; s < 68 * 17; s += 256) {
            int row = s / 17;
            int q = s - row * 17;
            int gy = ti + row, gx = tj + 4 * q;
            float4 v = make_float4(0.f, 0.f, 0.f, 0.f);
            if (gy < IN_SIZE && gx < IN_SIZE)
                v = *(const float4*)(x + c * XCH + gy * IN_SIZE + gx);
            *(float4*)(xs + row * 68 + 4 * q) = v;
        }
        __syncthreads();

        float w0[25];
#pragma unroll
        for (int q = 0; q < 25; q++) w0[q] = W0[c * 25 + q];

#pragma unroll
        for (int rr = 0; rr < 8; rr++) {
            int row = 4 * ty + rr;
            float xr[8];
            ((float4*)xr)[0] = *(const float4*)(xs + row * 68 + 4 * tx);
            ((float4*)xr)[1] = *(const float4*)(xs + row * 68 + 4 * tx + 4);
#pragma unroll
            for (int dy = 0; dy < 4; dy++) {
                int ki = rr - dy;
                if (ki >= 0 && ki <= 4) {
#pragma unroll
                    for (int kj = 0; kj < 5; kj++) {
                        float wv = w0[ki * 5 + kj];
#pragma unroll
                        for (int dx = 0; dx < 4; dx++)
                            acc[dy * 4 + dx] = fmaf(wv, xr[dx + kj], acc[dy * 4 + dx]);
                    }
                }
            }
        }
    }

    int gj = tj + 4 * tx;
    if (gj < NH) {
#pragma unroll
        for (int dy = 0; dy < 4; dy++) {
            int gi = ti + 4 * ty + dy;
            if (gi < NH)
                *(float4*)(out + oc * OUT_PLANE + gi * NH + gj) =
                    make_float4(acc[dy * 4], acc[dy * 4 + 1], acc[dy * 4 + 2], acc[dy * 4 + 3]);
        }
    }
}

// ------- Kernel 2: inhibition (fp32 in-place) + bf16 y copy + fused colsum -------
__global__ __launch_bounds__(256) void inhib_kernel(float* __restrict__ out,
                                                    uint16_t* __restrict__ yb,
                                                    float* __restrict__ colsum) {
    int p = blockIdx.x * 256 + threadIdx.x;
    bool valid = p < NB_TILES;
    int pc = valid ? p : 0;
    int i = pc / NH;
    int j = pc - i * NH;
    float v[OUT_CH];
    float m = 0.f;
#pragma unroll
    for (int oc = 0; oc < OUT_CH; oc++) {
        float t = valid ? out[oc * OUT_PLANE + p] : 0.f;
        t = fmaxf(t, 0.f);
        v[oc] = t;
        m = fmaxf(m, t);
    }
    float inv = 1.f / (m + 1e-9f);
    __shared__ float sm[OUT_CH * 4];
    const int lane = threadIdx.x & 63, wv = threadIdx.x >> 6;
#pragma unroll
    for (int oc = 0; oc < OUT_CH; oc++) {
        float t = v[oc] * inv;
        float t2 = t * t;
        t = t2 * t2 * t;
        if (valid) {
            out[oc * OUT_PLANE + p] = t;
            yb[oc * YSTRIDE + i * IN_SIZE + j] = f2bf(t);
        }
        float r = t;
        for (int off = 32; off; off >>= 1) r += __shfl_down(r, off);
        if (lane == 0) sm[oc * 4 + wv] = r;
    }
    __syncthreads();
    if (threadIdx.x < OUT_CH) {
        int oc = threadIdx.x;
        atomicAdd(colsum + oc, sm[oc * 4] + sm[oc * 4 + 1] + sm[oc * 4 + 2] + sm[oc * 4 + 3]);
    }
}

// ---------------- Kernel 3: fused GEMM y^T @ [xf | y] -> per-chunk partials ----------------
__device__ inline short8 unpack_b(const uint32_t* dw, int idx, int sh) {
    union { uint32_t u[4]; short8 s8; } bu;
#pragma unroll
    for (int t = 0; t < 4; t++)
        bu.u[t] = (uint32_t)((((uint64_t)dw[idx + t + 1] << 32) | dw[idx + t]) >> sh);
    return bu.s8;
}

__global__ __launch_bounds__(256) void gemm_kernel(const uint16_t* __restrict__ yb,
                                                   const uint16_t* __restrict__ xb,
                                                   float* __restrict__ Mpart) {
    const int lane = threadIdx.x & 63;
    const int rg = threadIdx.x >> 6;   // row-group (wave)
    const int l15 = lane & 15;
    const int kg = (lane >> 4) * 8;
    const int cb = blockIdx.x;         // 0..28 col-tile
    const int chunk = blockIdx.y;      // 0..27 k-chunk
    const int n = 16 * cb + l15;       // 0..463

    const uint16_t* pa = yb + (16 * rg + l15) * YSTRIDE + chunk * KCHUNK + kg;

    const uint16_t* pb;
    int idx, sh;
    if (n < 400) {  // xf column: n = (c, ki, kj)
        int c = n / 25;
        int r = n - 25 * c;
        int ki = r / 5;
        int kj = r - 5 * ki;
        pb = xb + c * XCH + ki * IN_SIZE + chunk * KCHUNK + kg;
        idx = kj >> 1;
        sh = (kj & 1) * 16;
    } else {  // y column (gram part): aligned, shift-0 path
        pb = yb + (n - 400) * YSTRIDE + chunk * KCHUNK + kg;
        idx = 0;
        sh = 0;
    }

    floatx4 acc = {0.f, 0.f, 0.f, 0.f};
    uint32_t dw[7];
    dw[6] = 0u;
    short8 a = *(const short8*)pa;
    *(uint4*)dw = *(const uint4*)pb;
    *(uint2*)(dw + 4) = *(const uint2*)(pb + 8);

#pragma unroll 2
    for (int s = 0; s < 54; s++) {
        pa += 32; pb += 32;
        short8 an = *(const short8*)pa;
        uint4 r0 = *(const uint4*)pb;
        uint2 r1 = *(const uint2*)(pb + 8);
        short8 b = unpack_b(dw, idx, sh);
        acc = __builtin_amdgcn_mfma_f32_16x16x32_bf16(a, b, acc, 0, 0, 0);
        a = an;
        *(uint4*)dw = r0;
        *(uint2*)(dw + 4) = r1;
    }
    short8 b = unpack_b(dw, idx, sh);
    acc = __builtin_amdgcn_mfma_f32_16x16x32_bf16(a, b, acc, 0, 0, 0);

    int row = 16 * rg + (lane >> 4) * 4;
    float* dst = Mpart + chunk * PSTRIDE + row * NTOT + n;
#pragma unroll
    for (int r = 0; r < 4; r++) dst[r * NTOT] = acc[r];
}

// ---------------- Kernel 4: reduce partials -> M (64x400) and yty (64x64) ----------------
__global__ __launch_bounds__(256) void reduce_kernel(const float* __restrict__ Mpart,
                                                     float* __restrict__ M,
                                                     float* __restrict__ yty) {
    int e = blockIdx.x * 256 + threadIdx.x;  // 0..29695 (116*256 exactly)
    float s = 0.f;
#pragma unroll 4
    for (int ch = 0; ch < NCHUNK; ch++) s += Mpart[ch * PSTRIDE + e];
    int row = e / NTOT, col = e - row * NTOT;
    if (col < 400) M[row * 400 + col] = s;
    else yty[row * 64 + (col - 400)] = s;
}

// ---------------- Kernel 5: Wfinal (+ fused exp_new/gfp) ----------------
__global__ __launch_bounds__(256) void finalize_w_kernel(const float* __restrict__ W,
                                                         const float* __restrict__ yty,
                                                         const float* __restrict__ M,
                                                         const float* __restrict__ colsum,
                                                         const float* __restrict__ exp_avg,
                                                         float* __restrict__ Wout,
                                                         float* __restrict__ expout) {
    __shared__ float gfps[OUT_CH];
    if (threadIdx.x < OUT_CH) {
        int o = threadIdx.x;
        float e = GAMMA_F * exp_avg[o] + ONE_MINUS_GAMMA * (colsum[o] / (float)NB_TILES);
        float s = e;
        for (int off = 32; off; off >>= 1) s += __shfl_down(s, off);
        s = __shfl(s, 0);
        float A = e / (s / (float)OUT_CH);
        gfps[o] = EPS_F * tanhf(-EPS_F * (A - 1.f)) + 1.f;
        if (blockIdx.x == 0) expout[o] = e;
    }
    __syncthreads();
    int idx = blockIdx.x * 256 + threadIdx.x;
    int o = idx / 400;
    int q = idx - o * 400;
    float dot = 0.f;
#pragma unroll 8
    for (int k = 0; k < OUT_CH; k++) dot = fmaf(yty[o * 64 + k], W[k * 400 + q], dot);
    float w = W[idx] + LR_OVER_NB * (M[idx] - dot);
    w = fmaxf(w, 0.f);
    float gp = gfps[o];
    float pos = (w > 0.f ? w : 0.f) * gp;
    float neg = (w < 0.f ? w : 0.f) / gp;
    Wout[idx] = pos + neg;
}

extern "C" void kernel_launch(void* const* d_in, const int* in_sizes, int n_in,
                              void* d_out, int out_size, void* d_ws, size_t ws_size,
                              hipStream_t stream) {
    const float* x = (const float*)d_in[0];
    const float* W = (const float*)d_in[1];
    const float* exp_avg = (const float*)d_in[2];
    float* out = (float*)d_out;

    float* wsf = (float*)d_ws;
    float* colsum = wsf;                       // 64
    float* M = wsf + 64;                       // 25600
    float* yty = wsf + 25664;                  // 4096
    float* Mpart = wsf + 29760;                // 28 * 29696 = 831488
    uint16_t* ybf = (uint16_t*)(wsf + 29760 + NCHUNK * PSTRIDE);  // 64*49280 bf16
    uint16_t* xbf = ybf + OUT_CH * YSTRIDE;                       // 802816 + 128 bf16

    float* Wout = out + OUT_CH * OUT_PLANE;
    float* expout = Wout + OUT_CH * IN_CH * KER * KER;

    hipMemsetAsync(colsum, 0, OUT_CH * sizeof(float), stream);

    xcast_kernel<<<784, 256, 0, stream>>>(x, xbf, ybf);
    conv_kernel<<<dim3(4, 4, 64), 256, 0, stream>>>(x, W, out);
    inhib_kernel<<<190, 256, 0, stream>>>(out, ybf, colsum);
    gemm_kernel<<<dim3(29, NCHUNK), 256, 0, stream>>>(ybf, xbf, Mpart);
    reduce_kernel<<<116, 256, 0, stream>>>(Mpart, M, yty);
    finalize_w_kernel<<<100, 256, 0, stream>>>(W, yty, M, colsum, exp_avg, Wout, expout);
}

// Round 7
// 202.653 us; speedup vs baseline: 1.6092x; 1.6092x over previous
//
#include <hip/hip_runtime.h>
#include <stdint.h>

#define IN_SIZE 224
#define KER 5
#define IN_CH 16
#define OUT_CH 64
#define NH 220
#define NB_TILES (NH * NH)       // 48400
#define XCH (IN_SIZE * IN_SIZE)  // 50176
#define OUT_PLANE NB_TILES
#define KP2 51200                // padded K: 64 chunks x 800
#define XS 52224                 // per-channel stride in shifted-x copies (>= 51200+896+32)
#define LR_OVER_NB ((float)(0.005 / 48400.0))
#define GAMMA_F 0.99f
#define ONE_MINUS_GAMMA 0.01f
#define EPS_F 0.01f

#define NCHUNK 64
#define CK 800                   // K per chunk = 25 steps of 32
#define PSTRIDE (64 * 512)       // partials: 64 rows x 512 cols per chunk

typedef __attribute__((ext_vector_type(8))) short short8;
typedef __attribute__((ext_vector_type(4))) float floatx4;

__device__ inline uint16_t f2bf(float f) {
    uint32_t u = __float_as_uint(f);
    return (uint16_t)((u + 0x7FFFu + ((u >> 16) & 1u)) >> 16);
}

// ---- Kernel 0: build 5 kj-shifted bf16 copies of x; zero y pads ----
__global__ __launch_bounds__(256) void xcast_kernel(const float* __restrict__ x,
                                                    uint16_t* __restrict__ xs,
                                                    uint16_t* __restrict__ yb) {
    int t = blockIdx.x * 256 + threadIdx.x;
    const int perq = XS / 4;  // 13056
    if (t < 5 * 16 * perq) {
        int kj = t / (16 * perq);
        int rem = t - kj * (16 * perq);
        int c = rem / perq;
        int q = (rem - c * perq) * 4;
        int base = c * XCH;
        ushort4 o;
        int i0 = q + kj;     o.x = f2bf(x[base + (i0 < XCH ? i0 : XCH - 1)]);
        int i1 = q + kj + 1; o.y = f2bf(x[base + (i1 < XCH ? i1 : XCH - 1)]);
        int i2 = q + kj + 2; o.z = f2bf(x[base + (i2 < XCH ? i2 : XCH - 1)]);
        int i3 = q + kj + 3; o.w = f2bf(x[base + (i3 < XCH ? i3 : XCH - 1)]);
        *(ushort4*)(xs + (kj * 16 + c) * XS + q) = o;
    }
    ushort4 z = {0, 0, 0, 0};
    if (t < 64 * 480) {  // zero yb K-tail [49280,51200) per row
        int r = t / 480, q = (t - r * 480) * 4;
        *(ushort4*)(yb + r * KP2 + 49280 + q) = z;
    }
    if (t < 64 * 220) {  // zero yb j-pad cols 220..223
        int o = t / 220, i = t - o * 220;
        *(ushort4*)(yb + o * KP2 + i * 224 + 220) = z;
    }
}

// ---- Kernel 1: conv, 64x64 tile, 4x4 micro-tile, 1 oc/block ----
__global__ __launch_bounds__(256) void conv_kernel(const float* __restrict__ x,
                                                   const float* __restrict__ W,
                                                   float* __restrict__ out) {
    __shared__ float xsh[68 * 68];
    const int tx = threadIdx.x & 15;
    const int ty = threadIdx.x >> 4;
    const int ti = blockIdx.y * 64;
    const int tj = blockIdx.x * 64;
    const int oc = blockIdx.z;

    float acc[16];
#pragma unroll
    for (int i = 0; i < 16; i++) acc[i] = 0.f;
    const float* W0 = W + oc * 400;

    for (int c = 0; c < IN_CH; c++) {
        __syncthreads();
        for (int s = threadIdx.x; s < 68 * 17; s += 256) {
            int row = s / 17;
            int q = s - row * 17;
            int gy = ti + row, gx = tj + 4 * q;
            float4 v = make_float4(0.f, 0.f, 0.f, 0.f);
            if (gy < IN_SIZE && gx < IN_SIZE)
                v = *(const float4*)(x + c * XCH + gy * IN_SIZE + gx);
            *(float4*)(xsh + row * 68 + 4 * q) = v;
        }
        __syncthreads();

        float w0[25];
#pragma unroll
        for (int q = 0; q < 25; q++) w0[q] = W0[c * 25 + q];

#pragma unroll
        for (int rr = 0; rr < 8; rr++) {
            int row = 4 * ty + rr;
            float xr[8];
            ((float4*)xr)[0] = *(const float4*)(xsh + row * 68 + 4 * tx);
            ((float4*)xr)[1] = *(const float4*)(xsh + row * 68 + 4 * tx + 4);
#pragma unroll
            for (int dy = 0; dy < 4; dy++) {
                int ki = rr - dy;
                if (ki >= 0 && ki <= 4) {
#pragma unroll
                    for (int kj = 0; kj < 5; kj++) {
                        float wv = w0[ki * 5 + kj];
#pragma unroll
                        for (int dx = 0; dx < 4; dx++)
                            acc[dy * 4 + dx] = fmaf(wv, xr[dx + kj], acc[dy * 4 + dx]);
                    }
                }
            }
        }
    }

    int gj = tj + 4 * tx;
    if (gj < NH) {
#pragma unroll
        for (int dy = 0; dy < 4; dy++) {
            int gi = ti + 4 * ty + dy;
            if (gi < NH)
                *(float4*)(out + oc * OUT_PLANE + gi * NH + gj) =
                    make_float4(acc[dy * 4], acc[dy * 4 + 1], acc[dy * 4 + 2], acc[dy * 4 + 3]);
        }
    }
}

// ---- Kernel 2: inhibition (fp32 in-place) + bf16 y copy + fused colsum ----
__global__ __launch_bounds__(128) void inhib_kernel(float* __restrict__ out,
                                                    uint16_t* __restrict__ yb,
                                                    float* __restrict__ colsum) {
    int p = blockIdx.x * 128 + threadIdx.x;
    bool valid = p < NB_TILES;
    int pc = valid ? p : 0;
    int i = pc / NH;
    int j = pc - i * NH;
    float v[OUT_CH];
    float m = 0.f;
#pragma unroll
    for (int oc = 0; oc < OUT_CH; oc++) {
        float t = valid ? out[oc * OUT_PLANE + p] : 0.f;
        t = fmaxf(t, 0.f);
        v[oc] = t;
        m = fmaxf(m, t);
    }
    float inv = 1.f / (m + 1e-9f);
    __shared__ float sm[OUT_CH * 2];
    const int lane = threadIdx.x & 63, wv = threadIdx.x >> 6;
#pragma unroll
    for (int oc = 0; oc < OUT_CH; oc++) {
        float t = v[oc] * inv;
        float t2 = t * t;
        t = t2 * t2 * t;
        if (valid) {
            out[oc * OUT_PLANE + p] = t;
            yb[oc * KP2 + i * 224 + j] = f2bf(t);
        }
        float r = t;
        for (int off = 32; off; off >>= 1) r += __shfl_down(r, off);
        if (lane == 0) sm[oc * 2 + wv] = r;
    }
    __syncthreads();
    if (threadIdx.x < OUT_CH) {
        int oc = threadIdx.x;
        atomicAdd(colsum + oc, sm[oc * 2] + sm[oc * 2 + 1]);
    }
}

// ---- Kernel 3: canonical LDS-staged GEMM  y^T(64xK) @ [xf|y](Kx464) ----
// grid (8 n-tiles, 64 k-chunks); per-chunk partials, no atomics.
__global__ __launch_bounds__(256) void gemm_kernel(const uint16_t* __restrict__ yb,
                                                   const uint16_t* __restrict__ xs,
                                                   float* __restrict__ Mpart) {
    __shared__ uint16_t As[2][64 * 40];
    __shared__ uint16_t Bs[2][64 * 40];
    const int tid = threadIdx.x;
    const int lane = tid & 63;
    const int w = tid >> 6;      // wave = m-group
    const int l15 = lane & 15;
    const int quad = lane >> 4;
    const int kg = quad * 8;
    const int ntile = blockIdx.x;  // 0..7
    const int chunk = blockIdx.y;  // 0..63
    const int k0 = chunk * CK;

    // staging assignment: thread -> (row/col sr, k-segment)
    const int sr = tid >> 2;           // 0..63
    const int sseg = (tid & 3) * 8;    // 0,8,16,24
    const uint16_t* pa = yb + sr * KP2 + k0 + sseg;

    int n_g = ntile * 64 + sr;
    const uint16_t* pbase;
    if (n_g < 400) {
        int c = n_g / 25;
        int r = n_g - 25 * c;
        int ki = r / 5;
        int kj = r - 5 * ki;
        pbase = xs + (kj * 16 + c) * XS + ki * 224;
    } else if (n_g < 464) {
        pbase = yb + (n_g - 400) * KP2;
    } else {
        pbase = yb;  // dead column, safe memory
    }
    const uint16_t* pb = pbase + k0 + sseg;

    floatx4 acc[4];
#pragma unroll
    for (int i = 0; i < 4; i++) acc[i] = (floatx4){0.f, 0.f, 0.f, 0.f};

    uint4 ra = *(const uint4*)pa;
    uint4 rb = *(const uint4*)pb;

    for (int s = 0; s < 25; s++) {
        const int p = s & 1;
        *(uint4*)&As[p][sr * 40 + sseg] = ra;
        *(uint4*)&Bs[p][sr * 40 + sseg] = rb;
        __syncthreads();
        if (s + 1 < 25) {
            pa += 32;
            pb += 32;
            ra = *(const uint4*)pa;
            rb = *(const uint4*)pb;
        }
        short8 af = *(const short8*)&As[p][(16 * w + l15) * 40 + kg];
#pragma unroll
        for (int ng = 0; ng < 4; ng++) {
            short8 bf = *(const short8*)&Bs[p][(16 * ng + l15) * 40 + kg];
            acc[ng] = __builtin_amdgcn_mfma_f32_16x16x32_bf16(af, bf, acc[ng], 0, 0, 0);
        }
        __syncthreads();
    }

    float* dst = Mpart + chunk * PSTRIDE;
#pragma unroll
    for (int ng = 0; ng < 4; ng++) {
        int col = ntile * 64 + ng * 16 + l15;
        if (col < 464) {
#pragma unroll
            for (int r = 0; r < 4; r++)
                dst[(16 * w + quad * 4 + r) * 512 + col] = acc[ng][r];
        }
    }
}

// ---- Kernel 4: reduce partials -> M (64x400) and yty (64x64) ----
__global__ __launch_bounds__(256) void reduce_kernel(const float* __restrict__ Mpart,
                                                     float* __restrict__ M,
                                                     float* __restrict__ yty) {
    int e = blockIdx.x * 256 + threadIdx.x;  // 0..32767
    float s = 0.f;
#pragma unroll 8
    for (int ch = 0; ch < NCHUNK; ch++) s += Mpart[ch * PSTRIDE + e];
    int row = e >> 9, col = e & 511;
    if (col < 400) M[row * 400 + col] = s;
    else if (col < 464) yty[row * 64 + (col - 400)] = s;
}

// ---- Kernel 5: Wfinal (+ fused exp_new/gfp) ----
__global__ __launch_bounds__(256) void finalize_w_kernel(const float* __restrict__ W,
                                                         const float* __restrict__ yty,
                                                         const float* __restrict__ M,
                                                         const float* __restrict__ colsum,
                                                         const float* __restrict__ exp_avg,
                                                         float* __restrict__ Wout,
                                                         float* __restrict__ expout) {
    __shared__ float gfps[OUT_CH];
    if (threadIdx.x < OUT_CH) {
        int o = threadIdx.x;
        float e = GAMMA_F * exp_avg[o] + ONE_MINUS_GAMMA * (colsum[o] / (float)NB_TILES);
        float s = e;
        for (int off = 32; off; off >>= 1) s += __shfl_down(s, off);
        s = __shfl(s, 0);
        float A = e / (s / (float)OUT_CH);
        gfps[o] = EPS_F * tanhf(-EPS_F * (A - 1.f)) + 1.f;
        if (blockIdx.x == 0) expout[o] = e;
    }
    __syncthreads();
    int idx = blockIdx.x * 256 + threadIdx.x;
    int o = idx / 400;
    int q = idx - o * 400;
    float dot = 0.f;
#pragma unroll 8
    for (int k = 0; k < OUT_CH; k++) dot = fmaf(yty[o * 64 + k], W[k * 400 + q], dot);
    float w = W[idx] + LR_OVER_NB * (M[idx] - dot);
    w = fmaxf(w, 0.f);
    float gp = gfps[o];
    float pos = (w > 0.f ? w : 0.f) * gp;
    float neg = (w < 0.f ? w : 0.f) / gp;
    Wout[idx] = pos + neg;
}

extern "C" void kernel_launch(void* const* d_in, const int* in_sizes, int n_in,
                              void* d_out, int out_size, void* d_ws, size_t ws_size,
                              hipStream_t stream) {
    const float* x = (const float*)d_in[0];
    const float* W = (const float*)d_in[1];
    const float* exp_avg = (const float*)d_in[2];
    float* out = (float*)d_out;

    float* wsf = (float*)d_ws;
    float* colsum = wsf;                        // 64
    float* M = wsf + 64;                        // 25600
    float* yty = wsf + 25664;                   // 4096 -> 29760
    float* Mpart = wsf + 29760;                 // 64 * 32768 = 2,097,152 fl
    uint16_t* ybf = (uint16_t*)(wsf + 29760 + NCHUNK * PSTRIDE);  // 64*51200 bf16
    uint16_t* xsb = ybf + OUT_CH * KP2;                            // 5*16*52224 bf16

    float* Wout = out + OUT_CH * OUT_PLANE;
    float* expout = Wout + OUT_CH * IN_CH * KER * KER;

    hipMemsetAsync(colsum, 0, OUT_CH * sizeof(float), stream);

    xcast_kernel<<<4080, 256, 0, stream>>>(x, xsb, ybf);
    conv_kernel<<<dim3(4, 4, 64), 256, 0, stream>>>(x, W, out);
    inhib_kernel<<<(NB_TILES + 127) / 128, 128, 0, stream>>>(out, ybf, colsum);
    gemm_kernel<<<dim3(8, NCHUNK), 256, 0, stream>>>(ybf, xsb, Mpart);
    reduce_kernel<<<128, 256, 0, stream>>>(Mpart, M, yty);
    finalize_w_kernel<<<100, 256, 0, stream>>>(W, yty, M, colsum, exp_avg, Wout, expout);
}

// Round 8
// 168.779 us; speedup vs baseline: 1.9322x; 1.2007x over previous
//
#include <hip/hip_runtime.h>
#include <stdint.h>

#define IN_SIZE 224
#define KER 5
#define IN_CH 16
#define OUT_CH 64
#define NH 220
#define NB_TILES (NH * NH)       // 48400
#define XCH (IN_SIZE * IN_SIZE)  // 50176
#define OUT_PLANE NB_TILES
#define KP2 51200                // padded K for gemm: 64 chunks x 800
#define XS 52224                 // per-plane stride in shifted-x copies
#define XTROWS 50304             // xT rows (XCH + pad for tap overhang)
#define LR_OVER_NB ((float)(0.005 / 48400.0))
#define GAMMA_F 0.99f
#define ONE_MINUS_GAMMA 0.01f
#define EPS_F 0.01f

#define NCHUNK 64
#define CK 800
#define PSTRIDE (64 * 512)

typedef __attribute__((ext_vector_type(8))) short short8;
typedef __attribute__((ext_vector_type(4))) float floatx4;

__device__ inline uint16_t f2bf(float f) {
    uint32_t u = __float_as_uint(f);
    return (uint16_t)((u + 0x7FFFu + ((u >> 16) & 1u)) >> 16);
}
__device__ inline float bf2f(uint16_t h) { return __uint_as_float((uint32_t)h << 16); }

// ---- Kernel 0: build 5 kj-shifted bf16 copies of x (gemm B-side); zero y pads ----
__global__ __launch_bounds__(256) void xcast_kernel(const float* __restrict__ x,
                                                    uint16_t* __restrict__ xs,
                                                    uint16_t* __restrict__ yb) {
    int t = blockIdx.x * 256 + threadIdx.x;
    const int perq = XS / 4;  // 13056
    if (t < 5 * 16 * perq) {
        int kj = t / (16 * perq);
        int rem = t - kj * (16 * perq);
        int c = rem / perq;
        int q = (rem - c * perq) * 4;
        int base = c * XCH;
        ushort4 o;
        int i0 = q + kj;     o.x = f2bf(x[base + (i0 < XCH ? i0 : XCH - 1)]);
        int i1 = q + kj + 1; o.y = f2bf(x[base + (i1 < XCH ? i1 : XCH - 1)]);
        int i2 = q + kj + 2; o.z = f2bf(x[base + (i2 < XCH ? i2 : XCH - 1)]);
        int i3 = q + kj + 3; o.w = f2bf(x[base + (i3 < XCH ? i3 : XCH - 1)]);
        *(ushort4*)(xs + (kj * 16 + c) * XS + q) = o;
    }
    ushort4 z = {0, 0, 0, 0};
    if (t < 64 * 480) {  // zero yb K-tail [49280,51200)
        int r = t / 480, q = (t - r * 480) * 4;
        *(ushort4*)(yb + r * KP2 + 49280 + q) = z;
    }
    if (t < 64 * 220) {  // zero yb j-pad cols 220..223
        int o = t / 220, i = t - o * 220;
        *(ushort4*)(yb + o * KP2 + i * 224 + 220) = z;
    }
}

// ---- Kernel 0b: xT[pixel][channel] hi/lo bf16 (conv B-side) ----
__global__ __launch_bounds__(256) void xt_kernel(const float* __restrict__ x,
                                                 uint16_t* __restrict__ xth,
                                                 uint16_t* __restrict__ xtl) {
    int addr = blockIdx.x * 256 + threadIdx.x;
    if (addr >= XTROWS) return;
    uint32_t dh[8], dl[8];
    if (addr < XCH) {
#pragma unroll
        for (int q = 0; q < 8; q++) {
            float v0 = x[(2 * q) * XCH + addr];
            float v1 = x[(2 * q + 1) * XCH + addr];
            uint16_t h0 = f2bf(v0), h1 = f2bf(v1);
            uint16_t l0 = f2bf(v0 - bf2f(h0)), l1 = f2bf(v1 - bf2f(h1));
            dh[q] = (uint32_t)h0 | ((uint32_t)h1 << 16);
            dl[q] = (uint32_t)l0 | ((uint32_t)l1 << 16);
        }
    } else {
#pragma unroll
        for (int q = 0; q < 8; q++) { dh[q] = 0u; dl[q] = 0u; }
    }
    *(uint4*)(xth + addr * 16) = make_uint4(dh[0], dh[1], dh[2], dh[3]);
    *(uint4*)(xth + addr * 16 + 8) = make_uint4(dh[4], dh[5], dh[6], dh[7]);
    *(uint4*)(xtl + addr * 16) = make_uint4(dl[0], dl[1], dl[2], dl[3]);
    *(uint4*)(xtl + addr * 16 + 8) = make_uint4(dl[4], dl[5], dl[6], dl[7]);
}

// ---- Kernel 0c: W repack into tap-pair MFMA layout, hi/lo ----
// Wrep[t][oc][k], k = s*16 + c, tap = 2t+s; tap 25 zero-padded.
__global__ __launch_bounds__(256) void wprep_kernel(const float* __restrict__ W,
                                                    uint16_t* __restrict__ wrh,
                                                    uint16_t* __restrict__ wrl) {
    int idx = blockIdx.x * 256 + threadIdx.x;  // 0..26623 = 13*2048
    int t = idx >> 11;
    int rem = idx & 2047;
    int oc = rem >> 5;
    int k = rem & 31;
    int s = k >> 4, c = k & 15;
    int tap = 2 * t + s;
    float v = (tap < 25) ? W[oc * 400 + c * 25 + tap] : 0.f;
    uint16_t h = f2bf(v);
    wrh[idx] = h;
    wrl[idx] = f2bf(v - bf2f(h));
}

// ---- Kernel 1: conv via MFMA, M=64 oc, N=64 padded positions, K=13 tap-pairs ----
__global__ __launch_bounds__(256) void conv_mfma_kernel(const uint16_t* __restrict__ xth,
                                                        const uint16_t* __restrict__ xtl,
                                                        const uint16_t* __restrict__ wrh,
                                                        const uint16_t* __restrict__ wrl,
                                                        float* __restrict__ out) {
    const int lane = threadIdx.x & 63;
    const int w = threadIdx.x >> 6;   // m-group: oc rows 16w..16w+15
    const int l15 = lane & 15;
    const int quad = lane >> 4;
    const int P0 = blockIdx.x * 64;
    const int c0 = (quad & 1) * 8;
    const int sq = quad >> 1;

    floatx4 acc[4];
#pragma unroll
    for (int g = 0; g < 4; g++) acc[g] = (floatx4){0.f, 0.f, 0.f, 0.f};

    const uint16_t* pah = wrh + (16 * w + l15) * 32 + quad * 8;
    const uint16_t* pal = wrl + (16 * w + l15) * 32 + quad * 8;

#pragma unroll
    for (int t = 0; t < 13; t++) {
        short8 ah = *(const short8*)(pah + t * 2048);
        short8 al = *(const short8*)(pal + t * 2048);
        const int tap0 = 2 * t, tap1 = 2 * t + 1;
        const int o0 = (tap0 / 5) * 224 + (tap0 % 5);
        const int o1 = (tap1 <= 24) ? (tap1 / 5) * 224 + (tap1 % 5) : 0;
        int off = sq ? o1 : o0;
#pragma unroll
        for (int g = 0; g < 4; g++) {
            int P = P0 + 16 * g + l15;
            const uint16_t* bph = xth + (P + off) * 16 + c0;
            const uint16_t* bpl = xtl + (P + off) * 16 + c0;
            short8 bh = *(const short8*)bph;
            short8 bl = *(const short8*)bpl;
            acc[g] = __builtin_amdgcn_mfma_f32_16x16x32_bf16(ah, bh, acc[g], 0, 0, 0);
            acc[g] = __builtin_amdgcn_mfma_f32_16x16x32_bf16(ah, bl, acc[g], 0, 0, 0);
            acc[g] = __builtin_amdgcn_mfma_f32_16x16x32_bf16(al, bh, acc[g], 0, 0, 0);
        }
    }

#pragma unroll
    for (int g = 0; g < 4; g++) {
        int P = P0 + 16 * g + l15;
        int i = P / 224;
        int j = P - i * 224;
        if (j < NH) {
            float* o = out + i * NH + j;
#pragma unroll
            for (int r = 0; r < 4; r++)
                o[(16 * w + quad * 4 + r) * OUT_PLANE] = acc[g][r];
        }
    }
}

// ---- Kernel 2: inhibition (fp32 in-place) + bf16 y copy + fused colsum ----
__global__ __launch_bounds__(128) void inhib_kernel(float* __restrict__ out,
                                                    uint16_t* __restrict__ yb,
                                                    float* __restrict__ colsum) {
    int p = blockIdx.x * 128 + threadIdx.x;
    bool valid = p < NB_TILES;
    int pc = valid ? p : 0;
    int i = pc / NH;
    int j = pc - i * NH;
    float v[OUT_CH];
    float m = 0.f;
#pragma unroll
    for (int oc = 0; oc < OUT_CH; oc++) {
        float t = valid ? out[oc * OUT_PLANE + p] : 0.f;
        t = fmaxf(t, 0.f);
        v[oc] = t;
        m = fmaxf(m, t);
    }
    float inv = 1.f / (m + 1e-9f);
    __shared__ float sm[OUT_CH * 2];
    const int lane = threadIdx.x & 63, wv = threadIdx.x >> 6;
#pragma unroll
    for (int oc = 0; oc < OUT_CH; oc++) {
        float t = v[oc] * inv;
        float t2 = t * t;
        t = t2 * t2 * t;
        if (valid) {
            out[oc * OUT_PLANE + p] = t;
            yb[oc * KP2 + i * 224 + j] = f2bf(t);
        }
        float r = t;
        for (int off = 32; off; off >>= 1) r += __shfl_down(r, off);
        if (lane == 0) sm[oc * 2 + wv] = r;
    }
    __syncthreads();
    if (threadIdx.x < OUT_CH) {
        int oc = threadIdx.x;
        atomicAdd(colsum + oc, sm[oc * 2] + sm[oc * 2 + 1]);
    }
}

// ---- Kernel 3: LDS-staged GEMM  y^T(64xK) @ [xf|y](Kx464), per-chunk partials ----
__global__ __launch_bounds__(256) void gemm_kernel(const uint16_t* __restrict__ yb,
                                                   const uint16_t* __restrict__ xs,
                                                   float* __restrict__ Mpart) {
    __shared__ uint16_t As[2][64 * 40];
    __shared__ uint16_t Bs[2][64 * 40];
    const int tid = threadIdx.x;
    const int lane = tid & 63;
    const int w = tid >> 6;
    const int l15 = lane & 15;
    const int quad = lane >> 4;
    const int kg = quad * 8;
    const int ntile = blockIdx.x;
    const int chunk = blockIdx.y;
    const int k0 = chunk * CK;

    const int sr = tid >> 2;
    const int sseg = (tid & 3) * 8;
    const uint16_t* pa = yb + sr * KP2 + k0 + sseg;

    int n_g = ntile * 64 + sr;
    const uint16_t* pbase;
    if (n_g < 400) {
        int c = n_g / 25;
        int r = n_g - 25 * c;
        int ki = r / 5;
        int kj = r - 5 * ki;
        pbase = xs + (kj * 16 + c) * XS + ki * 224;
    } else if (n_g < 464) {
        pbase = yb + (n_g - 400) * KP2;
    } else {
        pbase = yb;
    }
    const uint16_t* pb = pbase + k0 + sseg;

    floatx4 acc[4];
#pragma unroll
    for (int i = 0; i < 4; i++) acc[i] = (floatx4){0.f, 0.f, 0.f, 0.f};

    uint4 ra = *(const uint4*)pa;
    uint4 rb = *(const uint4*)pb;

    for (int s = 0; s < 25; s++) {
        const int p = s & 1;
        *(uint4*)&As[p][sr * 40 + sseg] = ra;
        *(uint4*)&Bs[p][sr * 40 + sseg] = rb;
        __syncthreads();
        if (s + 1 < 25) {
            pa += 32;
            pb += 32;
            ra = *(const uint4*)pa;
            rb = *(const uint4*)pb;
        }
        short8 af = *(const short8*)&As[p][(16 * w + l15) * 40 + kg];
#pragma unroll
        for (int ng = 0; ng < 4; ng++) {
            short8 bf = *(const short8*)&Bs[p][(16 * ng + l15) * 40 + kg];
            acc[ng] = __builtin_amdgcn_mfma_f32_16x16x32_bf16(af, bf, acc[ng], 0, 0, 0);
        }
        __syncthreads();
    }

    float* dst = Mpart + chunk * PSTRIDE;
#pragma unroll
    for (int ng = 0; ng < 4; ng++) {
        int col = ntile * 64 + ng * 16 + l15;
        if (col < 464) {
#pragma unroll
            for (int r = 0; r < 4; r++)
                dst[(16 * w + quad * 4 + r) * 512 + col] = acc[ng][r];
        }
    }
}

// ---- Kernel 4: reduce partials -> M (64x400) and yty (64x64) ----
__global__ __launch_bounds__(256) void reduce_kernel(const float* __restrict__ Mpart,
                                                     float* __restrict__ M,
                                                     float* __restrict__ yty) {
    int e = blockIdx.x * 256 + threadIdx.x;
    float s = 0.f;
#pragma unroll 8
    for (int ch = 0; ch < NCHUNK; ch++) s += Mpart[ch * PSTRIDE + e];
    int row = e >> 9, col = e & 511;
    if (col < 400) M[row * 400 + col] = s;
    else if (col < 464) yty[row * 64 + (col - 400)] = s;
}

// ---- Kernel 5: Wfinal (+ fused exp_new/gfp) ----
__global__ __launch_bounds__(256) void finalize_w_kernel(const float* __restrict__ W,
                                                         const float* __restrict__ yty,
                                                         const float* __restrict__ M,
                                                         const float* __restrict__ colsum,
                                                         const float* __restrict__ exp_avg,
                                                         float* __restrict__ Wout,
                                                         float* __restrict__ expout) {
    __shared__ float gfps[OUT_CH];
    if (threadIdx.x < OUT_CH) {
        int o = threadIdx.x;
        float e = GAMMA_F * exp_avg[o] + ONE_MINUS_GAMMA * (colsum[o] / (float)NB_TILES);
        float s = e;
        for (int off = 32; off; off >>= 1) s += __shfl_down(s, off);
        s = __shfl(s, 0);
        float A = e / (s / (float)OUT_CH);
        gfps[o] = EPS_F * tanhf(-EPS_F * (A - 1.f)) + 1.f;
        if (blockIdx.x == 0) expout[o] = e;
    }
    __syncthreads();
    int idx = blockIdx.x * 256 + threadIdx.x;
    int o = idx / 400;
    int q = idx - o * 400;
    float dot = 0.f;
#pragma unroll 8
    for (int k = 0; k < OUT_CH; k++) dot = fmaf(yty[o * 64 + k], W[k * 400 + q], dot);
    float w = W[idx] + LR_OVER_NB * (M[idx] - dot);
    w = fmaxf(w, 0.f);
    float gp = gfps[o];
    float pos = (w > 0.f ? w : 0.f) * gp;
    float neg = (w < 0.f ? w : 0.f) / gp;
    Wout[idx] = pos + neg;
}

extern "C" void kernel_launch(void* const* d_in, const int* in_sizes, int n_in,
                              void* d_out, int out_size, void* d_ws, size_t ws_size,
                              hipStream_t stream) {
    const float* x = (const float*)d_in[0];
    const float* W = (const float*)d_in[1];
    const float* exp_avg = (const float*)d_in[2];
    float* out = (float*)d_out;

    float* wsf = (float*)d_ws;
    float* colsum = wsf;                        // 64
    float* M = wsf + 64;                        // 25600
    float* yty = wsf + 25664;                   // 4096 -> 29760
    float* Mpart = wsf + 29760;                 // 64*32768 floats
    // conv-side buffers overlaid on Mpart (dead until gemm writes it; conv reads finish first)
    uint16_t* xth = (uint16_t*)Mpart;           // 50304*16
    uint16_t* xtl = xth + XTROWS * 16;          // 50304*16
    uint16_t* wrh = xtl + XTROWS * 16;          // 26624
    uint16_t* wrl = wrh + 26624;                // 26624  (total 3.3 MB < 8.4 MB)
    uint16_t* ybf = (uint16_t*)(wsf + 29760 + NCHUNK * PSTRIDE);  // 64*51200 bf16
    uint16_t* xsb = ybf + OUT_CH * KP2;                            // 5*16*52224 bf16

    float* Wout = out + OUT_CH * OUT_PLANE;
    float* expout = Wout + OUT_CH * IN_CH * KER * KER;

    hipMemsetAsync(colsum, 0, OUT_CH * sizeof(float), stream);

    xcast_kernel<<<4080, 256, 0, stream>>>(x, xsb, ybf);
    xt_kernel<<<(XTROWS + 255) / 256, 256, 0, stream>>>(x, xth, xtl);
    wprep_kernel<<<104, 256, 0, stream>>>(W, wrh, wrl);
    conv_mfma_kernel<<<770, 256, 0, stream>>>(xth, xtl, wrh, wrl, out);
    inhib_kernel<<<(NB_TILES + 127) / 128, 128, 0, stream>>>(out, ybf, colsum);
    gemm_kernel<<<dim3(8, NCHUNK), 256, 0, stream>>>(ybf, xsb, Mpart);
    reduce_kernel<<<128, 256, 0, stream>>>(Mpart, M, yty);
    finalize_w_kernel<<<100, 256, 0, stream>>>(W, yty, M, colsum, exp_avg, Wout, expout);
}